// Round 1
// 914.152 us; speedup vs baseline: 1.0556x; 1.0556x over previous
//
#include <hip/hip_runtime.h>

#define DEVFN __device__ __forceinline__

typedef float f32x4 __attribute__((ext_vector_type(4)));
typedef short bf16x8 __attribute__((ext_vector_type(8)));

constexpr int S = 4;
constexpr int T = 23;        // OUT_LEN - 1
constexpr int L = 24;
constexpr int BATCH = 16;
constexpr int H = 512;
constexpr int E = 512;
constexpr int V = 32000;
constexpr int G3 = 1536;     // 3*H
constexpr int KX = 1024;     // E+H
constexpr int F = 1536;      // E+2H
constexpr int MROWS = S * T * BATCH; // 1472
constexpr int MPAD = 1536;

constexpr int GRU_BPL = 8;           // blocks per line
constexpr int LDSW = 520;            // padded LDS row stride (shorts): 1040 B, bank-uniform

DEVFN float b2f(unsigned short h) {
    union { unsigned int u; float f; } c; c.u = ((unsigned int)h) << 16; return c.f;
}
DEVFN unsigned short f2b(float f) {
    union { float f; unsigned int u; } c; c.f = f;
    unsigned int u = c.u;
    return (unsigned short)((u + 0x7FFFu + ((u >> 16) & 1u)) >> 16);
}
DEVFN float sigmoidf_(float x) { return 1.0f / (1.0f + __expf(-x)); }
DEVFN float tanh_fast(float x) { return 1.0f - 2.0f / (__expf(2.0f * x) + 1.0f); }

DEVFN f32x4 mfma16(bf16x8 a, bf16x8 b, f32x4 c) {
    return __builtin_amdgcn_mfma_f32_16x16x32_bf16(a, b, c, 0, 0, 0);
}
DEVFN void gld16(const unsigned short* g, unsigned short* l) {
    __builtin_amdgcn_global_load_lds((const __attribute__((address_space(1))) void*)g,
                                     (__attribute__((address_space(3))) void*)l, 16, 0, 0);
}
DEVFN bf16x8 ldb8(const unsigned short* p) { return *(const bf16x8*)p; }

// ---------------------------------------------------------------------------
// fp32 -> bf16 bulk convert (round-to-nearest-even). n4 = n/4.
// ---------------------------------------------------------------------------
__global__ void f32_to_bf16(const float* __restrict__ src,
                            unsigned short* __restrict__ dst, int n4)
{
    const int i = blockIdx.x * blockDim.x + threadIdx.x;
    if (i >= n4) return;
    const float4 v = ((const float4*)src)[i];
    ushort4 o;
    o.x = f2b(v.x); o.y = f2b(v.y); o.z = f2b(v.z); o.w = f2b(v.w);
    ((ushort4*)dst)[i] = o;
}

// ---------------------------------------------------------------------------
// prep: gather emb rows (fp32->bf16) -> X + feats; ctx into X; agg into
// feats; h0 init (fp32 + bf16 hi/lo split); zero feats pad rows; zero the
// gru barrier counters (stream-ordered before gru_persist).
// grid = MPAD blocks x 128 threads.
// ---------------------------------------------------------------------------
__global__ void prep(
    const int* __restrict__ inp,           // [BATCH][S][L] int32
    const float* __restrict__ hidden,      // [S][BATCH][H] fp32
    const float* __restrict__ agg,         // [S][BATCH][H] fp32
    const float* __restrict__ emb,         // [V][E] fp32
    unsigned short* __restrict__ X,        // [S][T*BATCH][KX] bf16
    unsigned short* __restrict__ feats,    // [MPAD][F] bf16
    float* __restrict__ h0,                // [S][H][BATCH] fp32
    unsigned short* __restrict__ hhi0,     // [S][BATCH][H] bf16
    unsigned short* __restrict__ hlo0,
    int* __restrict__ bar)                 // [4*32] barrier counters
{
    const int r = blockIdx.x;
    const int tid = threadIdx.x; // 128
    if (r == 0 && tid < 128) bar[tid] = 0;
    if (r >= MROWS) {
        uint2* d = (uint2*)(feats + (size_t)r * F);
        for (int i = tid; i < F / 4; i += 128) d[i] = make_uint2(0u, 0u);
        return;
    }
    const int s = r / (T * BATCH);
    const int rem = r % (T * BATCH);
    const int t = rem >> 4, b = rem & 15;
    const int tok = inp[(b * S + s) * L + t];
    const float4 e = ((const float4*)(emb + (size_t)tok * E))[tid];
    ushort4 eb; eb.x = f2b(e.x); eb.y = f2b(e.y); eb.z = f2b(e.z); eb.w = f2b(e.w);
    ((ushort4*)(X + (size_t)r * KX))[tid] = eb;
    ((ushort4*)(feats + (size_t)r * F))[tid] = eb;
    const float* ctx = (s == 0) ? (agg + (size_t)b * H)
                                : (hidden + (size_t)(s * BATCH + b) * H);
    const float4 c = ((const float4*)ctx)[tid];
    ushort4 cb; cb.x = f2b(c.x); cb.y = f2b(c.y); cb.z = f2b(c.z); cb.w = f2b(c.w);
    ((ushort4*)(X + (size_t)r * KX))[128 + tid] = cb;
    const float4 g = ((const float4*)(agg + (size_t)(s * BATCH + b) * H))[tid];
    ushort4 gb; gb.x = f2b(g.x); gb.y = f2b(g.y); gb.z = f2b(g.z); gb.w = f2b(g.w);
    ((ushort4*)(feats + (size_t)r * F))[256 + tid] = gb;
    if (t == 0) {
        const float* hs = hidden + (size_t)(s * BATCH + b) * H;
#pragma unroll
        for (int jj = 0; jj < 4; ++jj) {
            const int j = tid * 4 + jj;
            const float hv = hs[j];
            h0[(size_t)(s * H + j) * BATCH + b] = hv;
            const unsigned short hb = f2b(hv);
            hhi0[(size_t)(s * BATCH + b) * H + j] = hb;
            hlo0[(size_t)(s * BATCH + b) * H + j] = f2b(hv - b2f(hb));
        }
    }
}

// ---------------------------------------------------------------------------
// gi = X @ W_ih^T + b_ih, per line. Output layout [S][T][G3][BATCH] fp32.
// grid = dim3(6, 23, 4) x 256 thr. wave = 1 Mtile x 4 Ntiles of 16x16.
// ---------------------------------------------------------------------------
__global__ __launch_bounds__(256) void gi_gemm(
    const unsigned short* __restrict__ X,    // [S][T*BATCH][KX] bf16
    const unsigned short* __restrict__ Wih,  // [S][G3][KX] bf16
    const float* __restrict__ bih,           // [S][G3] fp32
    float* __restrict__ gi)                  // [S][T][G3][BATCH]
{
    const int s = blockIdx.z, mt = blockIdx.y;
    const int w = threadIdx.x >> 6, l = threadIdx.x & 63;
    const int lm = l & 15, lq = l >> 4;
    const int nb = blockIdx.x * 256 + w * 64;
    const unsigned short* Arow = X + ((size_t)(s * T * BATCH + mt * 16 + lm)) * KX;
    f32x4 acc[4] = {};
#pragma unroll 4
    for (int k0 = 0; k0 < KX; k0 += 32) {
        bf16x8 a = ldb8(Arow + k0 + lq * 8);
#pragma unroll
        for (int n = 0; n < 4; ++n) {
            const unsigned short* Brow =
                Wih + ((size_t)(s * G3 + nb + n * 16 + lm)) * KX + k0 + lq * 8;
            acc[n] = mfma16(a, ldb8(Brow), acc[n]);
        }
    }
#pragma unroll
    for (int n = 0; n < 4; ++n) {
        const int g = nb + n * 16 + lm;
        const float bias = bih[s * G3 + g];
        f32x4 v;
#pragma unroll
        for (int r = 0; r < 4; ++r) v[r] = acc[n][r] + bias;
        *(f32x4*)&gi[((size_t)((s * T + mt) * G3 + g)) * BATCH + lq * 4] = v;
    }
}

// ---------------------------------------------------------------------------
// Persistent GRU: all T steps in ONE kernel.
// grid = 32 blocks x 256 thr; 8 blocks per line; wave = one 16-col jtile x 3
// gates with Whh fragments REGISTER-RESIDENT (48 bf16x8 = 192 VGPR). h state
// (hi/lo bf16) goes through global ping-pong + per-line 8-block barrier; each
// wave keeps its own f32 h tile in a persistent register. grid=32 <= 256 CUs
// so all blocks are co-resident; barrier is a monotonic device-scope counter
// (no reset within a launch; zeroed by prep each launch).
// ---------------------------------------------------------------------------
__global__ __launch_bounds__(256, 1) void gru_persist(
    const unsigned short* __restrict__ Whh,   // [S][G3][H] bf16
    const float* __restrict__ bhh,            // [S][G3]
    const float* __restrict__ gi,             // [S][T][G3][BATCH]
    const float* __restrict__ h0f,            // [S][H][BATCH] fp32 (init)
    unsigned short* __restrict__ hhi0,        // ping-pong parity 0 (init by prep)
    unsigned short* __restrict__ hlo0,
    unsigned short* __restrict__ hhi1,        // ping-pong parity 1
    unsigned short* __restrict__ hlo1,
    unsigned short* __restrict__ feats,       // [MPAD][F] bf16
    int* __restrict__ bar)                    // [4*32]
{
    __shared__ unsigned short lds_hi[16 * LDSW];
    __shared__ unsigned short lds_lo[16 * LDSW];

    const int s   = blockIdx.x >> 3;      // line
    const int blk = blockIdx.x & 7;
    const int tid = threadIdx.x;
    const int w = tid >> 6, l = tid & 63;
    const int lm = l & 15, lq = l >> 4;
    const int jt = blk * 4 + w;           // 0..31
    const int j0 = jt * 16;
    const int j  = j0 + lm;

    // ---- load this wave's Whh fragments into registers (once) ----
    bf16x8 wreg[3][16];
#pragma unroll
    for (int g = 0; g < 3; ++g)
#pragma unroll
        for (int c = 0; c < 16; ++c)
            wreg[g][c] = ldb8(Whh + ((size_t)(s * G3 + g * H + j)) * H + c * 32 + lq * 8);

    const float br_ = bhh[s * G3 + j];
    const float bz_ = bhh[s * G3 + H + j];
    const float bn_ = bhh[s * G3 + 2 * H + j];

    // persistent f32 h for this lane's (j, b=lq*4+r)
    f32x4 hreg = *(const f32x4*)&h0f[(size_t)(s * H + j) * BATCH + lq * 4];

    int* bars = bar + s * 32;             // 128 B apart per line

    for (int t = 0; t < T; ++t) {
        // ---- stage h[t&1] (written by prev step / prep) into padded LDS ----
        {
            const unsigned short* ghi = ((t & 1) ? hhi1 : hhi0) + (size_t)s * BATCH * H;
            const unsigned short* glo = ((t & 1) ? hlo1 : hlo0) + (size_t)s * BATCH * H;
#pragma unroll
            for (int it = 0; it < 4; ++it) {
                const int i = it * 256 + tid;          // chunk 0..1023
                const int b = i >> 6, k8 = i & 63;
                bf16x8 vh = ldb8(ghi + i * 8);
                bf16x8 vl = ldb8(glo + i * 8);
                *(bf16x8*)&lds_hi[b * LDSW + k8 * 8] = vh;
                *(bf16x8*)&lds_lo[b * LDSW + k8 * 8] = vl;
            }
        }
        __syncthreads();

        // ---- gh = h @ Whh^T for 3 gates (hi/lo split) ----
        f32x4 acc0 = {}, acc1 = {}, acc2 = {};
#pragma unroll
        for (int c = 0; c < 16; ++c) {
            bf16x8 ahi = *(const bf16x8*)&lds_hi[lm * LDSW + c * 32 + lq * 8];
            bf16x8 alo = *(const bf16x8*)&lds_lo[lm * LDSW + c * 32 + lq * 8];
            acc0 = mfma16(ahi, wreg[0][c], acc0);
            acc1 = mfma16(ahi, wreg[1][c], acc1);
            acc2 = mfma16(ahi, wreg[2][c], acc2);
            acc0 = mfma16(alo, wreg[0][c], acc0);
            acc1 = mfma16(alo, wreg[1][c], acc1);
            acc2 = mfma16(alo, wreg[2][c], acc2);
        }

        // ---- gates ----
        const size_t gibase = ((size_t)((s * T + t) * G3)) * BATCH;
        const f32x4 gir = *(const f32x4*)&gi[gibase + (size_t)j * BATCH + lq * 4];
        const f32x4 giz = *(const f32x4*)&gi[gibase + (size_t)(H + j) * BATCH + lq * 4];
        const f32x4 gin = *(const f32x4*)&gi[gibase + (size_t)(2 * H + j) * BATCH + lq * 4];
        f32x4 hnew;
#pragma unroll
        for (int r = 0; r < 4; ++r) {
            float rr = sigmoidf_(gir[r] + acc0[r] + br_);
            float zz = sigmoidf_(giz[r] + acc1[r] + bz_);
            float nn = tanh_fast(gin[r] + rr * (acc2[r] + bn_));
            hnew[r] = (1.0f - zz) * nn + zz * hreg[r];
        }
        hreg = hnew;

        // ---- publish h_new (hi/lo) to ping-pong[(t+1)&1] + feats ----
        unsigned short* ohi = (t & 1) ? hhi0 : hhi1;
        unsigned short* olo = (t & 1) ? hlo0 : hlo1;
#pragma unroll
        for (int r = 0; r < 4; ++r) {
            const int b = lq * 4 + r;
            const unsigned short hb = f2b(hnew[r]);
            ohi[((size_t)(s * BATCH + b)) * H + j] = hb;
            olo[((size_t)(s * BATCH + b)) * H + j] = f2b(hnew[r] - b2f(hb));
            feats[((size_t)(s * T * BATCH + t * 16 + b)) * F + E + j] = hb;
        }

        // ---- per-line barrier (skip after last step) ----
        if (t < T - 1) {
            __threadfence();                       // release our stores device-wide
            __syncthreads();
            if (tid == 0) {
                __hip_atomic_fetch_add(bars, 1, __ATOMIC_RELEASE, __HIP_MEMORY_SCOPE_AGENT);
                const int target = GRU_BPL * (t + 1);
                while (__hip_atomic_load(bars, __ATOMIC_ACQUIRE, __HIP_MEMORY_SCOPE_AGENT) < target) {
                    __builtin_amdgcn_s_sleep(1);
                }
            }
            __syncthreads();                       // acquire-side inval done by tid 0 covers CU L1/L2
        }
    }
}

// ---------------------------------------------------------------------------
// out[b][s][0][v] = (v==1) ? 1 : 0   (fp32)
// ---------------------------------------------------------------------------
__global__ void first_fill(float* __restrict__ out)
{
    const int row = blockIdx.y; // b*S+s in [0,64)
    const int v0 = (blockIdx.x * blockDim.x + threadIdx.x) * 4;
    if (v0 >= V) return;
    float4 val = make_float4(0.f, 0.f, 0.f, 0.f);
    if (v0 == 0) val.y = 1.0f;
    *(float4*)(out + (size_t)row * L * V + v0) = val;
}

// ---------------------------------------------------------------------------
// logits = feats @ fc_W^T + fc_b, scattered to out[b][s][t+1][v] (fp32).
// m97-style: 128x128 tile, BK=32, global_load_lds width 16, 4 waves, each
// 64x64 via 4x4 of 16x16x32 MFMA. grid = dim3(250, 12) x 256 thr.
// T1 XCD swizzle: nwg=3000 (3000%8==0, bijective); mt fast within each XCD
// chunk so the 12 blocks sharing one fcW B-panel run concurrently on one L2.
// ---------------------------------------------------------------------------
__global__ __launch_bounds__(256) void fc_gemm(
    const unsigned short* __restrict__ feats, // [MPAD][F] bf16
    const unsigned short* __restrict__ fcW,   // [V][F] bf16
    const float* __restrict__ fcb,            // [V] fp32
    float* __restrict__ out)                  // [BATCH][S][L][V] fp32
{
    __shared__ unsigned short As[128 * 32];
    __shared__ unsigned short Bs[128 * 32];
    constexpr int NT = V / 128;               // 250
    constexpr int MT = MPAD / 128;            // 12
    constexpr int NWG = NT * MT;              // 3000
    const int bid = blockIdx.y * NT + blockIdx.x;
    const int swz = (bid & 7) * (NWG / 8) + (bid >> 3);
    const int nt = swz / MT, mt = swz % MT;
    const int tid = threadIdx.x;
    const int w = tid >> 6, l = tid & 63;
    const int wr = w >> 1, wc = w & 1;
    const int lm = l & 15, lq = l >> 4;
    const unsigned short* Abase = feats + (size_t)(mt * 128) * F;
    const unsigned short* Bbase = fcW + (size_t)(nt * 128) * F;

    f32x4 acc[4][4] = {};

    for (int k0 = 0; k0 < F; k0 += 32) {
        __syncthreads();
#pragma unroll
        for (int i = 0; i < 2; ++i) {
            const int idx = i * 256 + tid;
            const int m = idx >> 2, kq = idx & 3;
            gld16(Abase + (size_t)m * F + k0 + kq * 8, &As[(size_t)(i * 256 + w * 64) * 8]);
            gld16(Bbase + (size_t)m * F + k0 + kq * 8, &Bs[(size_t)(i * 256 + w * 64) * 8]);
        }
        __syncthreads();
        bf16x8 af[4], bfr[4];
#pragma unroll
        for (int a = 0; a < 4; ++a) af[a] = ldb8(&As[(wr * 64 + a * 16 + lm) * 32 + lq * 8]);
#pragma unroll
        for (int b = 0; b < 4; ++b) bfr[b] = ldb8(&Bs[(wc * 64 + b * 16 + lm) * 32 + lq * 8]);
#pragma unroll
        for (int a = 0; a < 4; ++a)
#pragma unroll
            for (int b = 0; b < 4; ++b)
                acc[a][b] = mfma16(af[a], bfr[b], acc[a][b]);
    }

#pragma unroll
    for (int b = 0; b < 4; ++b) {
        const int col = nt * 128 + wc * 64 + b * 16 + lm;
        const float bias = fcb[col];
#pragma unroll
        for (int a = 0; a < 4; ++a) {
            const int mbase = mt * 128 + wr * 64 + a * 16 + lq * 4;
#pragma unroll
            for (int r = 0; r < 4; ++r) {
                const int m = mbase + r;
                if (m < MROWS) {
                    const int s = m / (T * BATCH);
                    const int rem = m % (T * BATCH);
                    const int t = rem >> 4, bb = rem & 15;
                    const size_t oidx = ((size_t)((bb * S + s) * L + (t + 1))) * V + col;
                    out[oidx] = acc[a][b][r] + bias;
                }
            }
        }
    }
}

// ---------------------------------------------------------------------------
extern "C" void kernel_launch(void* const* d_in, const int* in_sizes, int n_in,
                              void* d_out, int out_size, void* d_ws, size_t ws_size,
                              hipStream_t stream)
{
    const int* inp       = (const int*)d_in[0];
    const float* hidden  = (const float*)d_in[1];
    const float* agg     = (const float*)d_in[2];
    const float* emb     = (const float*)d_in[3];
    const float* Wih     = (const float*)d_in[4];
    const float* Whh     = (const float*)d_in[5];
    const float* bih     = (const float*)d_in[6];
    const float* bhh     = (const float*)d_in[7];
    const float* fcW     = (const float*)d_in[8];
    const float* fcb     = (const float*)d_in[9];
    float* out           = (float*)d_out;

    char* wsb = (char*)d_ws;
    unsigned short* X      = (unsigned short*)(wsb + 0);             // 3,014,656 B
    float* gi              = (float*)(wsb + 3014656);                // 9,043,968 B
    unsigned short* feats  = (unsigned short*)(wsb + 12058624);      // 4,718,592 B
    float* hb0             = (float*)(wsb + 16777216);               // 131,072 B
    int* bar               = (int*)(wsb + 16908288);                 // 512 B (was hb1)
    unsigned short* hh0    = (unsigned short*)(wsb + 17039360);      // 65,536 B
    unsigned short* hh1    = (unsigned short*)(wsb + 17104896);
    unsigned short* hl0    = (unsigned short*)(wsb + 17170432);
    unsigned short* hl1    = (unsigned short*)(wsb + 17235968);
    unsigned short* Wih_bf = (unsigned short*)(wsb + 17301504);      // 12,582,912 B
    unsigned short* Whh_bf = (unsigned short*)(wsb + 29884416);      //  6,291,456 B
    unsigned short* fcW_bf = (unsigned short*)(wsb + 36175872);      // 98,304,000 B
                                                                     // total 134,479,872 B

    // one-shot weight conversions fp32 -> bf16
    {
        const int n4w = S * G3 * KX / 4;   // 1,572,864
        f32_to_bf16<<<(n4w + 255) / 256, 256, 0, stream>>>(Wih, Wih_bf, n4w);
        const int n4h = S * G3 * H / 4;    //   786,432
        f32_to_bf16<<<(n4h + 255) / 256, 256, 0, stream>>>(Whh, Whh_bf, n4h);
        const int n4f = V * F / 4;         // 12,288,000
        f32_to_bf16<<<(n4f + 255) / 256, 256, 0, stream>>>(fcW, fcW_bf, n4f);
    }

    prep<<<MPAD, 128, 0, stream>>>(inp, hidden, agg, emb, X, feats, hb0, hh0, hl0, bar);
    gi_gemm<<<dim3(6, T, S), 256, 0, stream>>>(X, Wih_bf, bih, gi);

    // all 23 GRU steps in one persistent kernel (32 blocks, per-line barriers)
    gru_persist<<<32, 256, 0, stream>>>(Whh_bf, bhh, gi, hb0,
                                        hh0, hl0, hh1, hl1, feats, bar);

    first_fill<<<dim3((V / 4 + 255) / 256, 64), 256, 0, stream>>>(out);
    fc_gemm<<<dim3(V / 128, MPAD / 128), 256, 0, stream>>>(feats, fcW_bf, fcb, out);
}

// Round 2
// 821.502 us; speedup vs baseline: 1.1746x; 1.1128x over previous
//
#include <hip/hip_runtime.h>

#define DEVFN __device__ __forceinline__

typedef float f32x4 __attribute__((ext_vector_type(4)));
typedef short bf16x8 __attribute__((ext_vector_type(8)));
typedef unsigned int u32;
typedef unsigned long long u64;

constexpr int S = 4;
constexpr int T = 23;        // OUT_LEN - 1
constexpr int L = 24;
constexpr int BATCH = 16;
constexpr int H = 512;
constexpr int E = 512;
constexpr int V = 32000;
constexpr int G3 = 1536;     // 3*H
constexpr int KX = 1024;     // E+H
constexpr int F = 1536;      // E+2H
constexpr int MROWS = S * T * BATCH; // 1472
constexpr int MPAD = 1536;

constexpr int GRU_BPL = 8;           // blocks per line
constexpr int LDSW = 520;            // padded LDS row stride (shorts): 1040 B, bank-uniform
constexpr int SBH = S * BATCH * H;   // per-parity stride of packed h (u32 elems)

DEVFN float b2f(unsigned short h) {
    union { unsigned int u; float f; } c; c.u = ((unsigned int)h) << 16; return c.f;
}
DEVFN unsigned short f2b(float f) {
    union { float f; unsigned int u; } c; c.f = f;
    unsigned int u = c.u;
    return (unsigned short)((u + 0x7FFFu + ((u >> 16) & 1u)) >> 16);
}
DEVFN float sigmoidf_(float x) { return 1.0f / (1.0f + __expf(-x)); }
DEVFN float tanh_fast(float x) { return 1.0f - 2.0f / (__expf(2.0f * x) + 1.0f); }

DEVFN f32x4 mfma16(bf16x8 a, bf16x8 b, f32x4 c) {
    return __builtin_amdgcn_mfma_f32_16x16x32_bf16(a, b, c, 0, 0, 0);
}
DEVFN void gld16(const unsigned short* g, unsigned short* l) {
    __builtin_amdgcn_global_load_lds((const __attribute__((address_space(1))) void*)g,
                                     (__attribute__((address_space(3))) void*)l, 16, 0, 0);
}
DEVFN bf16x8 ldb8(const unsigned short* p) { return *(const bf16x8*)p; }

// coherent (L1/L2-bypassing) point accesses for intra-kernel cross-block traffic
DEVFN u64 coh_ld64(const u64* p) {
    return __hip_atomic_load(p, __ATOMIC_RELAXED, __HIP_MEMORY_SCOPE_AGENT);
}
DEVFN void coh_st32(u32* p, u32 v) {
    __hip_atomic_store(p, v, __ATOMIC_RELAXED, __HIP_MEMORY_SCOPE_AGENT);
}

// ---------------------------------------------------------------------------
// fp32 -> bf16 bulk convert (round-to-nearest-even). n4 = n/4.
// ---------------------------------------------------------------------------
__global__ void f32_to_bf16(const float* __restrict__ src,
                            unsigned short* __restrict__ dst, int n4)
{
    const int i = blockIdx.x * blockDim.x + threadIdx.x;
    if (i >= n4) return;
    const float4 v = ((const float4*)src)[i];
    ushort4 o;
    o.x = f2b(v.x); o.y = f2b(v.y); o.z = f2b(v.z); o.w = f2b(v.w);
    ((ushort4*)dst)[i] = o;
}

// ---------------------------------------------------------------------------
// prep: gather emb rows (fp32->bf16) -> X + feats; ctx into X; agg into
// feats; h0 init (fp32 + packed hi|lo bf16); zero feats pad rows; zero the
// gru barrier counters (stream-ordered before gru_persist).
// grid = MPAD blocks x 128 threads.
// ---------------------------------------------------------------------------
__global__ void prep(
    const int* __restrict__ inp,           // [BATCH][S][L] int32
    const float* __restrict__ hidden,      // [S][BATCH][H] fp32
    const float* __restrict__ agg,         // [S][BATCH][H] fp32
    const float* __restrict__ emb,         // [V][E] fp32
    unsigned short* __restrict__ X,        // [S][T*BATCH][KX] bf16
    unsigned short* __restrict__ feats,    // [MPAD][F] bf16
    float* __restrict__ h0,                // [S][H][BATCH] fp32
    u32* __restrict__ hpk,                 // [2][S][BATCH][H] packed hi<<16|lo
    int* __restrict__ bar)                 // [4*32] barrier counters
{
    const int r = blockIdx.x;
    const int tid = threadIdx.x; // 128
    if (r == 0 && tid < 128) bar[tid] = 0;
    if (r >= MROWS) {
        uint2* d = (uint2*)(feats + (size_t)r * F);
        for (int i = tid; i < F / 4; i += 128) d[i] = make_uint2(0u, 0u);
        return;
    }
    const int s = r / (T * BATCH);
    const int rem = r % (T * BATCH);
    const int t = rem >> 4, b = rem & 15;
    const int tok = inp[(b * S + s) * L + t];
    const float4 e = ((const float4*)(emb + (size_t)tok * E))[tid];
    ushort4 eb; eb.x = f2b(e.x); eb.y = f2b(e.y); eb.z = f2b(e.z); eb.w = f2b(e.w);
    ((ushort4*)(X + (size_t)r * KX))[tid] = eb;
    ((ushort4*)(feats + (size_t)r * F))[tid] = eb;
    const float* ctx = (s == 0) ? (agg + (size_t)b * H)
                                : (hidden + (size_t)(s * BATCH + b) * H);
    const float4 c = ((const float4*)ctx)[tid];
    ushort4 cb; cb.x = f2b(c.x); cb.y = f2b(c.y); cb.z = f2b(c.z); cb.w = f2b(c.w);
    ((ushort4*)(X + (size_t)r * KX))[128 + tid] = cb;
    const float4 g = ((const float4*)(agg + (size_t)(s * BATCH + b) * H))[tid];
    ushort4 gb; gb.x = f2b(g.x); gb.y = f2b(g.y); gb.z = f2b(g.z); gb.w = f2b(g.w);
    ((ushort4*)(feats + (size_t)r * F))[256 + tid] = gb;
    if (t == 0) {
        const float* hs = hidden + (size_t)(s * BATCH + b) * H;
#pragma unroll
        for (int jj = 0; jj < 4; ++jj) {
            const int j = tid * 4 + jj;
            const float hv = hs[j];
            h0[(size_t)(s * H + j) * BATCH + b] = hv;
            const unsigned short hb = f2b(hv);
            const unsigned short lb = f2b(hv - b2f(hb));
            hpk[((size_t)(s * BATCH + b)) * H + j] = ((u32)hb << 16) | lb;
        }
    }
}

// ---------------------------------------------------------------------------
// gi = X @ W_ih^T + b_ih, per line. Output layout [S][T][G3][BATCH] fp32.
// grid = dim3(6, 23, 4) x 256 thr. wave = 1 Mtile x 4 Ntiles of 16x16.
// ---------------------------------------------------------------------------
__global__ __launch_bounds__(256) void gi_gemm(
    const unsigned short* __restrict__ X,    // [S][T*BATCH][KX] bf16
    const unsigned short* __restrict__ Wih,  // [S][G3][KX] bf16
    const float* __restrict__ bih,           // [S][G3] fp32
    float* __restrict__ gi)                  // [S][T][G3][BATCH]
{
    const int s = blockIdx.z, mt = blockIdx.y;
    const int w = threadIdx.x >> 6, l = threadIdx.x & 63;
    const int lm = l & 15, lq = l >> 4;
    const int nb = blockIdx.x * 256 + w * 64;
    const unsigned short* Arow = X + ((size_t)(s * T * BATCH + mt * 16 + lm)) * KX;
    f32x4 acc[4] = {};
#pragma unroll 4
    for (int k0 = 0; k0 < KX; k0 += 32) {
        bf16x8 a = ldb8(Arow + k0 + lq * 8);
#pragma unroll
        for (int n = 0; n < 4; ++n) {
            const unsigned short* Brow =
                Wih + ((size_t)(s * G3 + nb + n * 16 + lm)) * KX + k0 + lq * 8;
            acc[n] = mfma16(a, ldb8(Brow), acc[n]);
        }
    }
#pragma unroll
    for (int n = 0; n < 4; ++n) {
        const int g = nb + n * 16 + lm;
        const float bias = bih[s * G3 + g];
        f32x4 v;
#pragma unroll
        for (int r = 0; r < 4; ++r) v[r] = acc[n][r] + bias;
        *(f32x4*)&gi[((size_t)((s * T + mt) * G3 + g)) * BATCH + lq * 4] = v;
    }
}

// ---------------------------------------------------------------------------
// Persistent GRU: all T steps in ONE kernel, FENCE-FREE.
// grid = 32 blocks x 256 thr; 8 blocks per line; wave = one 16-col jtile x 3
// gates with Whh fragments REGISTER-RESIDENT (48 bf16x8 = 192 VGPR).
// All cross-block traffic (packed h ping-pong + barrier counter) uses
// RELAXED agent-scope atomics only -> sc0/sc1 accesses that bypass the
// non-coherent L1/L2 point-wise. No __threadfence, so no per-step
// buffer_wbl2/buffer_inv L2 flush (that was ~11 us/step in round 1).
// Ordering: __syncthreads drains each wave's vmcnt before the tid0
// increment; the monotonic counter protocol has no ABA (a block increments
// only after its parity-p reads completed, so parity reuse at t+2 is safe).
// Line -> XCD-pair mapping: line = (bid&7)>>1 keeps the 8 line-mates on 2
// XCDs (perf heuristic only; correctness is atomic-based).
// ---------------------------------------------------------------------------
__global__ __launch_bounds__(256, 1) void gru_persist(
    const unsigned short* __restrict__ Whh,   // [S][G3][H] bf16
    const float* __restrict__ bhh,            // [S][G3]
    const float* __restrict__ gi,             // [S][T][G3][BATCH]
    const float* __restrict__ h0f,            // [S][H][BATCH] fp32 (init)
    u32* __restrict__ hpk,                    // [2][S][BATCH][H] packed
    unsigned short* __restrict__ feats,       // [MPAD][F] bf16
    int* __restrict__ bar)                    // [4*32]
{
    __shared__ unsigned short lds_hi[16 * LDSW];
    __shared__ unsigned short lds_lo[16 * LDSW];

    const int bid = blockIdx.x;
    const int s   = (bid & 7) >> 1;                 // line (XCD pair 2s,2s+1)
    const int blk = ((bid >> 3) << 1) | (bid & 1);  // 0..7 within line
    const int tid = threadIdx.x;
    const int w = tid >> 6, l = tid & 63;
    const int lm = l & 15, lq = l >> 4;
    const int jt = blk * 4 + w;           // 0..31
    const int j0 = jt * 16;
    const int j  = j0 + lm;

    // ---- load this wave's Whh fragments into registers (once) ----
    bf16x8 wreg[3][16];
#pragma unroll
    for (int g = 0; g < 3; ++g)
#pragma unroll
        for (int c = 0; c < 16; ++c)
            wreg[g][c] = ldb8(Whh + ((size_t)(s * G3 + g * H + j)) * H + c * 32 + lq * 8);

    const float br_ = bhh[s * G3 + j];
    const float bz_ = bhh[s * G3 + H + j];
    const float bn_ = bhh[s * G3 + 2 * H + j];

    // persistent f32 h for this lane's (j, b=lq*4+r)
    f32x4 hreg = *(const f32x4*)&h0f[(size_t)(s * H + j) * BATCH + lq * 4];

    int* bars = bar + s * 32;             // 128 B apart per line

    for (int t = 0; t < T; ++t) {
        // ---- stage packed h[t&1] into padded LDS (coherent loads) ----
        {
            const u32* src = hpk + (size_t)(t & 1) * SBH + (size_t)s * BATCH * H;
            const int b  = tid >> 4;          // 0..15
            const int jj = (tid & 15) * 32;   // 0,32,..,480
            const u64* sp = (const u64*)(src + (size_t)b * H + jj);
            unsigned short hibuf[32], lobuf[32];
#pragma unroll
            for (int k = 0; k < 16; ++k) {
                const u64 v = coh_ld64(&sp[k]);
                const u32 v0 = (u32)v, v1 = (u32)(v >> 32);
                lobuf[2 * k]     = (unsigned short)(v0 & 0xFFFFu);
                hibuf[2 * k]     = (unsigned short)(v0 >> 16);
                lobuf[2 * k + 1] = (unsigned short)(v1 & 0xFFFFu);
                hibuf[2 * k + 1] = (unsigned short)(v1 >> 16);
            }
#pragma unroll
            for (int k = 0; k < 4; ++k) {
                *(bf16x8*)&lds_hi[b * LDSW + jj + k * 8] = *(const bf16x8*)&hibuf[k * 8];
                *(bf16x8*)&lds_lo[b * LDSW + jj + k * 8] = *(const bf16x8*)&lobuf[k * 8];
            }
        }
        __syncthreads();

        // ---- gh = h @ Whh^T for 3 gates (hi/lo split) ----
        f32x4 acc0 = {}, acc1 = {}, acc2 = {};
#pragma unroll
        for (int c = 0; c < 16; ++c) {
            bf16x8 ahi = *(const bf16x8*)&lds_hi[lm * LDSW + c * 32 + lq * 8];
            bf16x8 alo = *(const bf16x8*)&lds_lo[lm * LDSW + c * 32 + lq * 8];
            acc0 = mfma16(ahi, wreg[0][c], acc0);
            acc1 = mfma16(ahi, wreg[1][c], acc1);
            acc2 = mfma16(ahi, wreg[2][c], acc2);
            acc0 = mfma16(alo, wreg[0][c], acc0);
            acc1 = mfma16(alo, wreg[1][c], acc1);
            acc2 = mfma16(alo, wreg[2][c], acc2);
        }

        // ---- gates ----
        const size_t gibase = ((size_t)((s * T + t) * G3)) * BATCH;
        const f32x4 gir = *(const f32x4*)&gi[gibase + (size_t)j * BATCH + lq * 4];
        const f32x4 giz = *(const f32x4*)&gi[gibase + (size_t)(H + j) * BATCH + lq * 4];
        const f32x4 gin = *(const f32x4*)&gi[gibase + (size_t)(2 * H + j) * BATCH + lq * 4];
        f32x4 hnew;
#pragma unroll
        for (int r = 0; r < 4; ++r) {
            float rr = sigmoidf_(gir[r] + acc0[r] + br_);
            float zz = sigmoidf_(giz[r] + acc1[r] + bz_);
            float nn = tanh_fast(gin[r] + rr * (acc2[r] + bn_));
            hnew[r] = (1.0f - zz) * nn + zz * hreg[r];
        }
        hreg = hnew;

        // ---- publish h_new: feats (normal) + packed ping-pong (coherent) ----
        if (t < T - 1) {
            u32* dst = hpk + (size_t)((t + 1) & 1) * SBH + (size_t)s * BATCH * H;
#pragma unroll
            for (int r = 0; r < 4; ++r) {
                const int b = lq * 4 + r;
                const unsigned short hb = f2b(hnew[r]);
                const unsigned short lb = f2b(hnew[r] - b2f(hb));
                feats[((size_t)(s * T * BATCH + t * 16 + b)) * F + E + j] = hb;
                coh_st32(&dst[(size_t)b * H + j], ((u32)hb << 16) | lb);
            }
            // barrier: drain this wave's stores, then monotonic counter
            asm volatile("s_waitcnt vmcnt(0)" ::: "memory");
            __syncthreads();
            if (tid == 0) {
                __hip_atomic_fetch_add(bars, 1, __ATOMIC_RELAXED, __HIP_MEMORY_SCOPE_AGENT);
                const int target = GRU_BPL * (t + 1);
                while (__hip_atomic_load(bars, __ATOMIC_RELAXED, __HIP_MEMORY_SCOPE_AGENT) < target)
                    __builtin_amdgcn_s_sleep(1);
            }
            __syncthreads();
        } else {
#pragma unroll
            for (int r = 0; r < 4; ++r) {
                const int b = lq * 4 + r;
                feats[((size_t)(s * T * BATCH + t * 16 + b)) * F + E + j] = f2b(hnew[r]);
            }
        }
    }
}

// ---------------------------------------------------------------------------
// out[b][s][0][v] = (v==1) ? 1 : 0   (fp32)
// ---------------------------------------------------------------------------
__global__ void first_fill(float* __restrict__ out)
{
    const int row = blockIdx.y; // b*S+s in [0,64)
    const int v0 = (blockIdx.x * blockDim.x + threadIdx.x) * 4;
    if (v0 >= V) return;
    float4 val = make_float4(0.f, 0.f, 0.f, 0.f);
    if (v0 == 0) val.y = 1.0f;
    *(float4*)(out + (size_t)row * L * V + v0) = val;
}

// ---------------------------------------------------------------------------
// logits = feats @ fc_W^T + fc_b, scattered to out[b][s][t+1][v] (fp32).
// m97-style: 128x128 tile, BK=32, global_load_lds width 16, 4 waves, each
// 64x64 via 4x4 of 16x16x32 MFMA. grid = dim3(250, 12) x 256 thr.
// T1 XCD swizzle: nwg=3000 (3000%8==0, bijective); mt fast within each XCD
// chunk so the 12 blocks sharing one fcW B-panel run concurrently on one L2.
// ---------------------------------------------------------------------------
__global__ __launch_bounds__(256) void fc_gemm(
    const unsigned short* __restrict__ feats, // [MPAD][F] bf16
    const unsigned short* __restrict__ fcW,   // [V][F] bf16
    const float* __restrict__ fcb,            // [V] fp32
    float* __restrict__ out)                  // [BATCH][S][L][V] fp32
{
    __shared__ unsigned short As[128 * 32];
    __shared__ unsigned short Bs[128 * 32];
    constexpr int NT = V / 128;               // 250
    constexpr int MT = MPAD / 128;            // 12
    constexpr int NWG = NT * MT;              // 3000
    const int bid = blockIdx.y * NT + blockIdx.x;
    const int swz = (bid & 7) * (NWG / 8) + (bid >> 3);
    const int nt = swz / MT, mt = swz % MT;
    const int tid = threadIdx.x;
    const int w = tid >> 6, l = tid & 63;
    const int wr = w >> 1, wc = w & 1;
    const int lm = l & 15, lq = l >> 4;
    const unsigned short* Abase = feats + (size_t)(mt * 128) * F;
    const unsigned short* Bbase = fcW + (size_t)(nt * 128) * F;

    f32x4 acc[4][4] = {};

    for (int k0 = 0; k0 < F; k0 += 32) {
        __syncthreads();
#pragma unroll
        for (int i = 0; i < 2; ++i) {
            const int idx = i * 256 + tid;
            const int m = idx >> 2, kq = idx & 3;
            gld16(Abase + (size_t)m * F + k0 + kq * 8, &As[(size_t)(i * 256 + w * 64) * 8]);
            gld16(Bbase + (size_t)m * F + k0 + kq * 8, &Bs[(size_t)(i * 256 + w * 64) * 8]);
        }
        __syncthreads();
        bf16x8 af[4], bfr[4];
#pragma unroll
        for (int a = 0; a < 4; ++a) af[a] = ldb8(&As[(wr * 64 + a * 16 + lm) * 32 + lq * 8]);
#pragma unroll
        for (int b = 0; b < 4; ++b) bfr[b] = ldb8(&Bs[(wc * 64 + b * 16 + lm) * 32 + lq * 8]);
#pragma unroll
        for (int a = 0; a < 4; ++a)
#pragma unroll
            for (int b = 0; b < 4; ++b)
                acc[a][b] = mfma16(af[a], bfr[b], acc[a][b]);
    }

#pragma unroll
    for (int b = 0; b < 4; ++b) {
        const int col = nt * 128 + wc * 64 + b * 16 + lm;
        const float bias = fcb[col];
#pragma unroll
        for (int a = 0; a < 4; ++a) {
            const int mbase = mt * 128 + wr * 64 + a * 16 + lq * 4;
#pragma unroll
            for (int r = 0; r < 4; ++r) {
                const int m = mbase + r;
                if (m < MROWS) {
                    const int s = m / (T * BATCH);
                    const int rem = m % (T * BATCH);
                    const int t = rem >> 4, bb = rem & 15;
                    const size_t oidx = ((size_t)((bb * S + s) * L + (t + 1))) * V + col;
                    out[oidx] = acc[a][b][r] + bias;
                }
            }
        }
    }
}

// ---------------------------------------------------------------------------
extern "C" void kernel_launch(void* const* d_in, const int* in_sizes, int n_in,
                              void* d_out, int out_size, void* d_ws, size_t ws_size,
                              hipStream_t stream)
{
    const int* inp       = (const int*)d_in[0];
    const float* hidden  = (const float*)d_in[1];
    const float* agg     = (const float*)d_in[2];
    const float* emb     = (const float*)d_in[3];
    const float* Wih     = (const float*)d_in[4];
    const float* Whh     = (const float*)d_in[5];
    const float* bih     = (const float*)d_in[6];
    const float* bhh     = (const float*)d_in[7];
    const float* fcW     = (const float*)d_in[8];
    const float* fcb     = (const float*)d_in[9];
    float* out           = (float*)d_out;

    char* wsb = (char*)d_ws;
    unsigned short* X      = (unsigned short*)(wsb + 0);             // 3,014,656 B
    float* gi              = (float*)(wsb + 3014656);                // 9,043,968 B
    unsigned short* feats  = (unsigned short*)(wsb + 12058624);      // 4,718,592 B
    float* hb0             = (float*)(wsb + 16777216);               // 131,072 B
    int* bar               = (int*)(wsb + 16908288);                 // 512 B
    u32* hpk               = (u32*)(wsb + 17039360);                 // 262,144 B ([2][S][B][H])
    unsigned short* Wih_bf = (unsigned short*)(wsb + 17301504);      // 12,582,912 B
    unsigned short* Whh_bf = (unsigned short*)(wsb + 29884416);      //  6,291,456 B
    unsigned short* fcW_bf = (unsigned short*)(wsb + 36175872);      // 98,304,000 B
                                                                     // total 134,479,872 B

    // one-shot weight conversions fp32 -> bf16
    {
        const int n4w = S * G3 * KX / 4;   // 1,572,864
        f32_to_bf16<<<(n4w + 255) / 256, 256, 0, stream>>>(Wih, Wih_bf, n4w);
        const int n4h = S * G3 * H / 4;    //   786,432
        f32_to_bf16<<<(n4h + 255) / 256, 256, 0, stream>>>(Whh, Whh_bf, n4h);
        const int n4f = V * F / 4;         // 12,288,000
        f32_to_bf16<<<(n4f + 255) / 256, 256, 0, stream>>>(fcW, fcW_bf, n4f);
    }

    prep<<<MPAD, 128, 0, stream>>>(inp, hidden, agg, emb, X, feats, hb0, hpk, bar);
    gi_gemm<<<dim3(6, T, S), 256, 0, stream>>>(X, Wih_bf, bih, gi);

    // all 23 GRU steps in one persistent kernel (32 blocks, fence-free barriers)
    gru_persist<<<32, 256, 0, stream>>>(Whh_bf, bhh, gi, hb0, hpk, feats, bar);

    first_fill<<<dim3((V / 4 + 255) / 256, 64), 256, 0, stream>>>(out);
    fc_gemm<<<dim3(V / 128, MPAD / 128), 256, 0, stream>>>(feats, fcW_bf, fcb, out);
}

// Round 3
// 793.166 us; speedup vs baseline: 1.2166x; 1.0357x over previous
//
#include <hip/hip_runtime.h>

#define DEVFN __device__ __forceinline__

typedef float f32x4 __attribute__((ext_vector_type(4)));
typedef short bf16x8 __attribute__((ext_vector_type(8)));
typedef unsigned int u32;
typedef unsigned long long u64;

constexpr int S = 4;
constexpr int T = 23;        // OUT_LEN - 1
constexpr int L = 24;
constexpr int BATCH = 16;
constexpr int H = 512;
constexpr int E = 512;
constexpr int V = 32000;
constexpr int G3 = 1536;     // 3*H
constexpr int KX = 1024;     // E+H
constexpr int F = 1536;      // E+2H
constexpr int MROWS = S * T * BATCH; // 1472
constexpr int MPAD = 1536;

constexpr int GRU_BPL = 8;           // blocks per line
constexpr int LDSW = 520;            // padded LDS row stride (shorts)
constexpr int SBH = S * BATCH * H;   // per-parity stride of packed h (u32 elems)

DEVFN float b2f(unsigned short h) {
    union { unsigned int u; float f; } c; c.u = ((unsigned int)h) << 16; return c.f;
}
DEVFN unsigned short f2b(float f) {
    union { float f; unsigned int u; } c; c.f = f;
    unsigned int u = c.u;
    return (unsigned short)((u + 0x7FFFu + ((u >> 16) & 1u)) >> 16);
}
DEVFN float sigmoidf_(float x) { return 1.0f / (1.0f + __expf(-x)); }
DEVFN float tanh_fast(float x) { return 1.0f - 2.0f / (__expf(2.0f * x) + 1.0f); }

DEVFN f32x4 mfma16(bf16x8 a, bf16x8 b, f32x4 c) {
    return __builtin_amdgcn_mfma_f32_16x16x32_bf16(a, b, c, 0, 0, 0);
}
DEVFN void gld16(const unsigned short* g, unsigned short* l) {
    __builtin_amdgcn_global_load_lds((const __attribute__((address_space(1))) void*)g,
                                     (__attribute__((address_space(3))) void*)l, 16, 0, 0);
}
DEVFN bf16x8 ldb8(const unsigned short* p) { return *(const bf16x8*)p; }

// coherent (L1/L2-bypassing) point accesses for intra-kernel cross-block traffic
DEVFN u64 coh_ld64(const u64* p) {
    return __hip_atomic_load(p, __ATOMIC_RELAXED, __HIP_MEMORY_SCOPE_AGENT);
}
DEVFN void coh_st32(u32* p, u32 v) {
    __hip_atomic_store(p, v, __ATOMIC_RELAXED, __HIP_MEMORY_SCOPE_AGENT);
}

// ---------------------------------------------------------------------------
// fp32 -> bf16 bulk convert (round-to-nearest-even). n4 = n/4.
// ---------------------------------------------------------------------------
__global__ void f32_to_bf16(const float* __restrict__ src,
                            unsigned short* __restrict__ dst, int n4)
{
    const int i = blockIdx.x * blockDim.x + threadIdx.x;
    if (i >= n4) return;
    const float4 v = ((const float4*)src)[i];
    ushort4 o;
    o.x = f2b(v.x); o.y = f2b(v.y); o.z = f2b(v.z); o.w = f2b(v.w);
    ((ushort4*)dst)[i] = o;
}

// ---------------------------------------------------------------------------
// prep: gather emb rows (fp32->bf16) -> X + feats; ctx into X; agg into
// feats; h0 init (fp32 + packed hi|lo bf16); zero feats pad rows; zero the
// gru barrier counters.
// grid = MPAD blocks x 128 threads.
// ---------------------------------------------------------------------------
__global__ void prep(
    const int* __restrict__ inp,           // [BATCH][S][L] int32
    const float* __restrict__ hidden,      // [S][BATCH][H] fp32
    const float* __restrict__ agg,         // [S][BATCH][H] fp32
    const float* __restrict__ emb,         // [V][E] fp32
    unsigned short* __restrict__ X,        // [S][T*BATCH][KX] bf16
    unsigned short* __restrict__ feats,    // [MPAD][F] bf16
    float* __restrict__ h0,                // [S][H][BATCH] fp32
    u32* __restrict__ hpk,                 // [2][S][BATCH][H] packed hi<<16|lo
    int* __restrict__ bar)                 // [4*32] barrier counters
{
    const int r = blockIdx.x;
    const int tid = threadIdx.x; // 128
    if (r == 0 && tid < 128) bar[tid] = 0;
    if (r >= MROWS) {
        uint2* d = (uint2*)(feats + (size_t)r * F);
        for (int i = tid; i < F / 4; i += 128) d[i] = make_uint2(0u, 0u);
        return;
    }
    const int s = r / (T * BATCH);
    const int rem = r % (T * BATCH);
    const int t = rem >> 4, b = rem & 15;
    const int tok = inp[(b * S + s) * L + t];
    const float4 e = ((const float4*)(emb + (size_t)tok * E))[tid];
    ushort4 eb; eb.x = f2b(e.x); eb.y = f2b(e.y); eb.z = f2b(e.z); eb.w = f2b(e.w);
    ((ushort4*)(X + (size_t)r * KX))[tid] = eb;
    ((ushort4*)(feats + (size_t)r * F))[tid] = eb;
    const float* ctx = (s == 0) ? (agg + (size_t)b * H)
                                : (hidden + (size_t)(s * BATCH + b) * H);
    const float4 c = ((const float4*)ctx)[tid];
    ushort4 cb; cb.x = f2b(c.x); cb.y = f2b(c.y); cb.z = f2b(c.z); cb.w = f2b(c.w);
    ((ushort4*)(X + (size_t)r * KX))[128 + tid] = cb;
    const float4 g = ((const float4*)(agg + (size_t)(s * BATCH + b) * H))[tid];
    ushort4 gb; gb.x = f2b(g.x); gb.y = f2b(g.y); gb.z = f2b(g.z); gb.w = f2b(g.w);
    ((ushort4*)(feats + (size_t)r * F))[256 + tid] = gb;
    if (t == 0) {
        const float* hs = hidden + (size_t)(s * BATCH + b) * H;
#pragma unroll
        for (int jj = 0; jj < 4; ++jj) {
            const int j = tid * 4 + jj;
            const float hv = hs[j];
            h0[(size_t)(s * H + j) * BATCH + b] = hv;
            const unsigned short hb = f2b(hv);
            const unsigned short lb = f2b(hv - b2f(hb));
            hpk[((size_t)(s * BATCH + b)) * H + j] = ((u32)hb << 16) | lb;
        }
    }
}

// ---------------------------------------------------------------------------
// gi = X @ W_ih^T + b_ih, per line. Output layout [S][T][G3][BATCH] fp32.
// grid = dim3(6, 23, 4) x 256 thr. wave = 1 Mtile x 4 Ntiles of 16x16.
// ---------------------------------------------------------------------------
__global__ __launch_bounds__(256) void gi_gemm(
    const unsigned short* __restrict__ X,    // [S][T*BATCH][KX] bf16
    const unsigned short* __restrict__ Wih,  // [S][G3][KX] bf16
    const float* __restrict__ bih,           // [S][G3] fp32
    float* __restrict__ gi)                  // [S][T][G3][BATCH]
{
    const int s = blockIdx.z, mt = blockIdx.y;
    const int w = threadIdx.x >> 6, l = threadIdx.x & 63;
    const int lm = l & 15, lq = l >> 4;
    const int nb = blockIdx.x * 256 + w * 64;
    const unsigned short* Arow = X + ((size_t)(s * T * BATCH + mt * 16 + lm)) * KX;
    f32x4 acc[4] = {};
#pragma unroll 4
    for (int k0 = 0; k0 < KX; k0 += 32) {
        bf16x8 a = ldb8(Arow + k0 + lq * 8);
#pragma unroll
        for (int n = 0; n < 4; ++n) {
            const unsigned short* Brow =
                Wih + ((size_t)(s * G3 + nb + n * 16 + lm)) * KX + k0 + lq * 8;
            acc[n] = mfma16(a, ldb8(Brow), acc[n]);
        }
    }
#pragma unroll
    for (int n = 0; n < 4; ++n) {
        const int g = nb + n * 16 + lm;
        const float bias = bih[s * G3 + g];
        f32x4 v;
#pragma unroll
        for (int r = 0; r < 4; ++r) v[r] = acc[n][r] + bias;
        *(f32x4*)&gi[((size_t)((s * T + mt) * G3 + g)) * BATCH + lq * 4] = v;
    }
}

// ---------------------------------------------------------------------------
// Persistent GRU: all T steps in ONE kernel, FENCE-FREE (see round-2 notes).
// ---------------------------------------------------------------------------
__global__ __launch_bounds__(256, 1) void gru_persist(
    const unsigned short* __restrict__ Whh,   // [S][G3][H] bf16
    const float* __restrict__ bhh,            // [S][G3]
    const float* __restrict__ gi,             // [S][T][G3][BATCH]
    const float* __restrict__ h0f,            // [S][H][BATCH] fp32 (init)
    u32* __restrict__ hpk,                    // [2][S][BATCH][H] packed
    unsigned short* __restrict__ feats,       // [MPAD][F] bf16
    int* __restrict__ bar)                    // [4*32]
{
    __shared__ unsigned short lds_hi[16 * LDSW];
    __shared__ unsigned short lds_lo[16 * LDSW];

    const int bid = blockIdx.x;
    const int s   = (bid & 7) >> 1;                 // line (XCD pair 2s,2s+1)
    const int blk = ((bid >> 3) << 1) | (bid & 1);  // 0..7 within line
    const int tid = threadIdx.x;
    const int w = tid >> 6, l = tid & 63;
    const int lm = l & 15, lq = l >> 4;
    const int jt = blk * 4 + w;           // 0..31
    const int j0 = jt * 16;
    const int j  = j0 + lm;

    // ---- load this wave's Whh fragments into registers (once) ----
    bf16x8 wreg[3][16];
#pragma unroll
    for (int g = 0; g < 3; ++g)
#pragma unroll
        for (int c = 0; c < 16; ++c)
            wreg[g][c] = ldb8(Whh + ((size_t)(s * G3 + g * H + j)) * H + c * 32 + lq * 8);

    const float br_ = bhh[s * G3 + j];
    const float bz_ = bhh[s * G3 + H + j];
    const float bn_ = bhh[s * G3 + 2 * H + j];

    // persistent f32 h for this lane's (j, b=lq*4+r)
    f32x4 hreg = *(const f32x4*)&h0f[(size_t)(s * H + j) * BATCH + lq * 4];

    int* bars = bar + s * 32;             // 128 B apart per line

    for (int t = 0; t < T; ++t) {
        // ---- stage packed h[t&1] into padded LDS (coherent loads) ----
        {
            const u32* src = hpk + (size_t)(t & 1) * SBH + (size_t)s * BATCH * H;
            const int b  = tid >> 4;          // 0..15
            const int jj = (tid & 15) * 32;   // 0,32,..,480
            const u64* sp = (const u64*)(src + (size_t)b * H + jj);
            unsigned short hibuf[32], lobuf[32];
#pragma unroll
            for (int k = 0; k < 16; ++k) {
                const u64 v = coh_ld64(&sp[k]);
                const u32 v0 = (u32)v, v1 = (u32)(v >> 32);
                lobuf[2 * k]     = (unsigned short)(v0 & 0xFFFFu);
                hibuf[2 * k]     = (unsigned short)(v0 >> 16);
                lobuf[2 * k + 1] = (unsigned short)(v1 & 0xFFFFu);
                hibuf[2 * k + 1] = (unsigned short)(v1 >> 16);
            }
#pragma unroll
            for (int k = 0; k < 4; ++k) {
                *(bf16x8*)&lds_hi[b * LDSW + jj + k * 8] = *(const bf16x8*)&hibuf[k * 8];
                *(bf16x8*)&lds_lo[b * LDSW + jj + k * 8] = *(const bf16x8*)&lobuf[k * 8];
            }
        }
        __syncthreads();

        // ---- gh = h @ Whh^T for 3 gates (hi/lo split) ----
        f32x4 acc0 = {}, acc1 = {}, acc2 = {};
#pragma unroll
        for (int c = 0; c < 16; ++c) {
            bf16x8 ahi = *(const bf16x8*)&lds_hi[lm * LDSW + c * 32 + lq * 8];
            bf16x8 alo = *(const bf16x8*)&lds_lo[lm * LDSW + c * 32 + lq * 8];
            acc0 = mfma16(ahi, wreg[0][c], acc0);
            acc1 = mfma16(ahi, wreg[1][c], acc1);
            acc2 = mfma16(ahi, wreg[2][c], acc2);
            acc0 = mfma16(alo, wreg[0][c], acc0);
            acc1 = mfma16(alo, wreg[1][c], acc1);
            acc2 = mfma16(alo, wreg[2][c], acc2);
        }

        // ---- gates ----
        const size_t gibase = ((size_t)((s * T + t) * G3)) * BATCH;
        const f32x4 gir = *(const f32x4*)&gi[gibase + (size_t)j * BATCH + lq * 4];
        const f32x4 giz = *(const f32x4*)&gi[gibase + (size_t)(H + j) * BATCH + lq * 4];
        const f32x4 gin = *(const f32x4*)&gi[gibase + (size_t)(2 * H + j) * BATCH + lq * 4];
        f32x4 hnew;
#pragma unroll
        for (int r = 0; r < 4; ++r) {
            float rr = sigmoidf_(gir[r] + acc0[r] + br_);
            float zz = sigmoidf_(giz[r] + acc1[r] + bz_);
            float nn = tanh_fast(gin[r] + rr * (acc2[r] + bn_));
            hnew[r] = (1.0f - zz) * nn + zz * hreg[r];
        }
        hreg = hnew;

        // ---- publish h_new: feats (normal) + packed ping-pong (coherent) ----
        if (t < T - 1) {
            u32* dst = hpk + (size_t)((t + 1) & 1) * SBH + (size_t)s * BATCH * H;
#pragma unroll
            for (int r = 0; r < 4; ++r) {
                const int b = lq * 4 + r;
                const unsigned short hb = f2b(hnew[r]);
                const unsigned short lb = f2b(hnew[r] - b2f(hb));
                feats[((size_t)(s * T * BATCH + t * 16 + b)) * F + E + j] = hb;
                coh_st32(&dst[(size_t)b * H + j], ((u32)hb << 16) | lb);
            }
            // barrier: drain this wave's stores, then monotonic counter
            asm volatile("s_waitcnt vmcnt(0)" ::: "memory");
            __syncthreads();
            if (tid == 0) {
                __hip_atomic_fetch_add(bars, 1, __ATOMIC_RELAXED, __HIP_MEMORY_SCOPE_AGENT);
                const int target = GRU_BPL * (t + 1);
                while (__hip_atomic_load(bars, __ATOMIC_RELAXED, __HIP_MEMORY_SCOPE_AGENT) < target)
                    __builtin_amdgcn_s_sleep(1);
            }
            __syncthreads();
        } else {
#pragma unroll
            for (int r = 0; r < 4; ++r) {
                const int b = lq * 4 + r;
                feats[((size_t)(s * T * BATCH + t * 16 + b)) * F + E + j] = f2b(hnew[r]);
            }
        }
    }
}

// ---------------------------------------------------------------------------
// out[b][s][0][v] = (v==1) ? 1 : 0   (fp32)
// ---------------------------------------------------------------------------
__global__ void first_fill(float* __restrict__ out)
{
    const int row = blockIdx.y; // b*S+s in [0,64)
    const int v0 = (blockIdx.x * blockDim.x + threadIdx.x) * 4;
    if (v0 >= V) return;
    float4 val = make_float4(0.f, 0.f, 0.f, 0.f);
    if (v0 == 0) val.y = 1.0f;
    *(float4*)(out + (size_t)row * L * V + v0) = val;
}

// ---------------------------------------------------------------------------
// fc logits GEMM, 256x256 tile, BK=64, 512 thr (8 waves = 2Mx4N), phase-
// pipelined (T2 row-XOR swizzle + T3/T4 counted vmcnt + T5 setprio).
// LDS 128 KiB dynamic: As[2][256][64] + Bs[2][256][64] bf16.
// Staging: gld16 linear dest, inverse-swizzled global src chunk kb^(row&7);
// reads: asm ds_read_b128 at chunk kb^(row&7) -> conflict-minimal.
// Pipeline: burst-stage tile kt+2 after tile kt's last barrier; tile-top
// s_waitcnt vmcnt(8) (= exactly next tile's loads outstanding); last tile
// peeled with vmcnt(0). 4 phases/tile x 16 MFMA, barrier per phase.
// grid = 750 (bijective XCD swizzle, mt fast), out scatter as before.
// ---------------------------------------------------------------------------
__global__ __launch_bounds__(512, 1) void fc_gemm8(
    const unsigned short* __restrict__ feats, // [MPAD][F] bf16
    const unsigned short* __restrict__ fcW,   // [V][F] bf16
    const float* __restrict__ fcb,            // [V] fp32
    float* __restrict__ out)                  // [BATCH][S][L][V] fp32
{
    extern __shared__ unsigned short lds[];   // 131072 B
    unsigned short* As = lds;                 // [2][16384]
    unsigned short* Bs = lds + 32768;         // [2][16384]

    constexpr int MTt = MPAD / 256;           // 6
    constexpr int NK = F / 64;                // 24 K-tiles

    // bijective XCD swizzle for 750 wgs: q=93, r=6 (m204 variant)
    const int orig = blockIdx.x;
    const int xcd = orig & 7, lin = orig >> 3;
    const int wg = (xcd < 6 ? xcd * 94 : 564 + (xcd - 6) * 93) + lin;
    const int nt = wg / MTt, mt = wg % MTt;

    const int tid = threadIdx.x;
    const int wid = tid >> 6, lane = tid & 63;
    const int wr = wid >> 2, wc = wid & 3;    // 2 M-waves x 4 N-waves
    const int lm = lane & 15, lq = lane >> 4;
    const int sw = lm & 7;                    // row&7 == lm&7 for all frag rows

    const unsigned short* Abase = feats + (size_t)(mt * 256) * F;
    const unsigned short* Bbase = fcW + (size_t)(nt * 256) * F;

    f32x4 acc[8][4] = {};
    bf16x8 af[4][2];       // A frags: 4 mf x 2 kk (current m-half)
    bf16x8 bfr[2][2][2];   // B frags: [nh][nf][kk], both n-halves live

    // stage one K-tile (64 cols) of A and B into buffer d
    auto STAGE = [&](int kt, int d) {
        const int k0 = kt * 64;
#pragma unroll
        for (int i = 0; i < 4; ++i) {
            const int idx = i * 512 + tid;
            const int row = idx >> 3, kbp = idx & 7;
            const int kg = kbp ^ (row & 7);          // inverse swizzle on source
            const int wub = (i * 512 + wid * 64) * 8; // wave-uniform LDS base
            gld16(Abase + (size_t)row * F + k0 + kg * 8, As + d * 16384 + wub);
            gld16(Bbase + (size_t)row * F + k0 + kg * 8, Bs + d * 16384 + wub);
        }
    };

    auto LDA = [&](int d, int mh) {
#pragma unroll
        for (int mf = 0; mf < 4; ++mf)
#pragma unroll
            for (int kk = 0; kk < 2; ++kk) {
                const int ra = wr * 128 + mh * 64 + mf * 16 + lm;
                const unsigned a =
                    (unsigned)(size_t)(As + d * 16384 + ra * 64 + (((kk * 4 + lq) ^ sw) * 8));
                asm volatile("ds_read_b128 %0, %1" : "=v"(af[mf][kk]) : "v"(a));
            }
    };
    auto LDB = [&](int d, int nh) {
#pragma unroll
        for (int nf = 0; nf < 2; ++nf)
#pragma unroll
            for (int kk = 0; kk < 2; ++kk) {
                const int rb = wc * 64 + nh * 32 + nf * 16 + lm;
                const unsigned a =
                    (unsigned)(size_t)(Bs + d * 16384 + rb * 64 + (((kk * 4 + lq) ^ sw) * 8));
                asm volatile("ds_read_b128 %0, %1" : "=v"(bfr[nh][nf][kk]) : "v"(a));
            }
    };
    auto MMQ = [&](int mh, int nh) {
        __builtin_amdgcn_s_setprio(1);
#pragma unroll
        for (int mf = 0; mf < 4; ++mf)
#pragma unroll
            for (int nf = 0; nf < 2; ++nf)
#pragma unroll
                for (int kk = 0; kk < 2; ++kk)
                    acc[mh * 4 + mf][nh * 2 + nf] =
                        mfma16(af[mf][kk], bfr[nh][nf][kk], acc[mh * 4 + mf][nh * 2 + nf]);
        __builtin_amdgcn_s_setprio(0);
    };

#define LGKM0() do { asm volatile("s_waitcnt lgkmcnt(0)" ::: "memory"); \
                     __builtin_amdgcn_sched_barrier(0); } while (0)

    STAGE(0, 0);
    STAGE(1, 1);                                   // 16 loads outstanding

    for (int kt = 0; kt < NK - 1; ++kt) {
        const int d = kt & 1;
        asm volatile("s_waitcnt vmcnt(8)" ::: "memory");  // tile kt landed
        __builtin_amdgcn_s_barrier();
        // P0: A(mh0) + B(nh0) reads, quadrant (0,0)
        LDA(d, 0); LDB(d, 0);
        LGKM0(); MMQ(0, 0);
        __builtin_amdgcn_s_barrier();
        // P1: B(nh1) reads, quadrant (0,1)
        LDB(d, 1);
        LGKM0(); MMQ(0, 1);
        __builtin_amdgcn_s_barrier();
        // P2: A(mh1) reads, quadrant (1,0)
        LDA(d, 1);
        LGKM0(); MMQ(1, 0);
        __builtin_amdgcn_s_barrier();
        // P3: quadrant (1,1), no reads
        MMQ(1, 1);
        __builtin_amdgcn_s_barrier();              // all reads of buf d done
        if (kt < NK - 2) STAGE(kt + 2, d);         // burst next-next tile
    }
    {   // peeled last tile (kt = NK-1, d = 1)
        asm volatile("s_waitcnt vmcnt(0)" ::: "memory");
        __builtin_amdgcn_s_barrier();
        LDA(1, 0); LDB(1, 0); LGKM0(); MMQ(0, 0);
        LDB(1, 1); LGKM0(); MMQ(0, 1);
        LDA(1, 1); LGKM0(); MMQ(1, 0);
        MMQ(1, 1);
    }
#undef LGKM0

    // epilogue: bias + scatter
#pragma unroll
    for (int nfg = 0; nfg < 4; ++nfg) {
        const int col = nt * 256 + wc * 64 + nfg * 16 + lm;
        const float bias = fcb[col];
#pragma unroll
        for (int mfg = 0; mfg < 8; ++mfg) {
            const int mbase = mt * 256 + wr * 128 + mfg * 16 + lq * 4;
#pragma unroll
            for (int r = 0; r < 4; ++r) {
                const int m = mbase + r;
                if (m < MROWS) {
                    const int sx = m / (T * BATCH);
                    const int rem = m % (T * BATCH);
                    const int tt = rem >> 4, bb = rem & 15;
                    const size_t oidx = ((size_t)((bb * S + sx) * L + (tt + 1))) * V + col;
                    out[oidx] = acc[mfg][nfg][r] + bias;
                }
            }
        }
    }
}

// ---------------------------------------------------------------------------
extern "C" void kernel_launch(void* const* d_in, const int* in_sizes, int n_in,
                              void* d_out, int out_size, void* d_ws, size_t ws_size,
                              hipStream_t stream)
{
    const int* inp       = (const int*)d_in[0];
    const float* hidden  = (const float*)d_in[1];
    const float* agg     = (const float*)d_in[2];
    const float* emb     = (const float*)d_in[3];
    const float* Wih     = (const float*)d_in[4];
    const float* Whh     = (const float*)d_in[5];
    const float* bih     = (const float*)d_in[6];
    const float* bhh     = (const float*)d_in[7];
    const float* fcW     = (const float*)d_in[8];
    const float* fcb     = (const float*)d_in[9];
    float* out           = (float*)d_out;

    char* wsb = (char*)d_ws;
    unsigned short* X      = (unsigned short*)(wsb + 0);             // 3,014,656 B
    float* gi              = (float*)(wsb + 3014656);                // 9,043,968 B
    unsigned short* feats  = (unsigned short*)(wsb + 12058624);      // 4,718,592 B
    float* hb0             = (float*)(wsb + 16777216);               // 131,072 B
    int* bar               = (int*)(wsb + 16908288);                 // 512 B
    u32* hpk               = (u32*)(wsb + 17039360);                 // 262,144 B ([2][S][B][H])
    unsigned short* Wih_bf = (unsigned short*)(wsb + 17301504);      // 12,582,912 B
    unsigned short* Whh_bf = (unsigned short*)(wsb + 29884416);      //  6,291,456 B
    unsigned short* fcW_bf = (unsigned short*)(wsb + 36175872);      // 98,304,000 B
                                                                     // total 134,479,872 B

    // allow 128 KiB dynamic LDS for fc_gemm8 (host-side attr, capture-safe)
    static bool s_attr = false;
    if (!s_attr) {
        (void)hipFuncSetAttribute(reinterpret_cast<const void*>(fc_gemm8),
                                  hipFuncAttributeMaxDynamicSharedMemorySize, 131072);
        s_attr = true;
    }

    // one-shot weight conversions fp32 -> bf16
    {
        const int n4w = S * G3 * KX / 4;   // 1,572,864
        f32_to_bf16<<<(n4w + 255) / 256, 256, 0, stream>>>(Wih, Wih_bf, n4w);
        const int n4h = S * G3 * H / 4;    //   786,432
        f32_to_bf16<<<(n4h + 255) / 256, 256, 0, stream>>>(Whh, Whh_bf, n4h);
        const int n4f = V * F / 4;         // 12,288,000
        f32_to_bf16<<<(n4f + 255) / 256, 256, 0, stream>>>(fcW, fcW_bf, n4f);
    }

    prep<<<MPAD, 128, 0, stream>>>(inp, hidden, agg, emb, X, feats, hb0, hpk, bar);
    gi_gemm<<<dim3(6, T, S), 256, 0, stream>>>(X, Wih_bf, bih, gi);

    // all 23 GRU steps in one persistent kernel (32 blocks, fence-free barriers)
    gru_persist<<<32, 256, 0, stream>>>(Whh_bf, bhh, gi, hb0, hpk, feats, bar);

    first_fill<<<dim3((V / 4 + 255) / 256, 64), 256, 0, stream>>>(out);
    fc_gemm8<<<dim3(750), 512, 131072, stream>>>(feats, fcW_bf, fcb, out);
}